// Round 1
// baseline (111.777 us; speedup 1.0000x reference)
//
#include <hip/hip_runtime.h>
#include <math.h>

#define GRIDN 1024
#define NAGENTS 262144
#define CCH 8
#define HIDDEN 64
#define DT 0.1f
#define DECAYF 0.99f
#define SENSOR_LEN 3.0f
// cos(0.6), sin(0.6)
#define COS_SA 0.82533561490967829724f
#define SIN_SA 0.56464247339503535720f

__global__ void __launch_bounds__(256) k_init_winner(int* __restrict__ winner) {
    int i = blockIdx.x * blockDim.x + threadIdx.x;
    ((int4*)winner)[i] = make_int4(-1, -1, -1, -1);
}

__global__ void __launch_bounds__(256) k_winner(const float* __restrict__ pos,
                                                int* __restrict__ winner) {
    int i = blockIdx.x * blockDim.x + threadIdx.x;
    int gx = (int)rintf(pos[i]) & (GRIDN - 1);
    int gy = (int)rintf(pos[i + NAGENTS]) & (GRIDN - 1);
    atomicMax(&winner[(gx << 10) + gy], i);
}

// BT[x][y][c] = 3x3 torus box sum of lattice channel c at (x,y)
__global__ void __launch_bounds__(256) k_boxT(const float* __restrict__ lat,
                                              float* __restrict__ BT) {
    int idx = blockIdx.x * blockDim.x + threadIdx.x;  // 0 .. 1M-1
    int x = idx >> 10, y = idx & (GRIDN - 1);
    int xm = (x + GRIDN - 1) & (GRIDN - 1), xp = (x + 1) & (GRIDN - 1);
    int ym = (y + GRIDN - 1) & (GRIDN - 1), yp = (y + 1) & (GRIDN - 1);
    float out[CCH];
#pragma unroll
    for (int c = 0; c < CCH; ++c) {
        const float* L = lat + (size_t)c * GRIDN * GRIDN;
        const float* r0 = L + xm * GRIDN;
        const float* r1 = L + x * GRIDN;
        const float* r2 = L + xp * GRIDN;
        out[c] = r0[ym] + r0[y] + r0[yp]
               + r1[ym] + r1[y] + r1[yp]
               + r2[ym] + r2[y] + r2[yp];
    }
    float4* dst = (float4*)(BT + (size_t)idx * CCH);
    dst[0] = make_float4(out[0], out[1], out[2], out[3]);
    dst[1] = make_float4(out[4], out[5], out[6], out[7]);
}

__global__ void __launch_bounds__(256) k_agent(
    const float* __restrict__ pos, const float* __restrict__ vel,
    const float* __restrict__ BT,
    const float* __restrict__ W1, const float* __restrict__ b1,
    const float* __restrict__ W2, const float* __restrict__ b2,
    float* __restrict__ out_pos, float* __restrict__ out_vel,
    float* __restrict__ dp) {
    int i = blockIdx.x * blockDim.x + threadIdx.x;
    float px = pos[i], py = pos[i + NAGENTS];
    float vx = vel[i], vy = vel[i + NAGENTS];

    float r2 = vx * vx + vy * vy;
    float ct, st;
    if (r2 > 0.f) {
        float inv = rsqrtf(r2);
        ct = vx * inv;
        st = vy * inv;
    } else {
        ct = 1.f;  // atan2(0,0) = 0
        st = 0.f;
    }

    // sensor direction cosines: front, +0.6 (left), -0.6 (right)
    float dirx[3], diry[3];
    dirx[0] = ct;                          diry[0] = st;
    dirx[1] = ct * COS_SA - st * SIN_SA;   diry[1] = st * COS_SA + ct * SIN_SA;
    dirx[2] = ct * COS_SA + st * SIN_SA;   diry[2] = st * COS_SA - ct * SIN_SA;

    float xin[3 * CCH];
#pragma unroll
    for (int s = 0; s < 3; ++s) {
        int gx = ((int)rintf(px + SENSOR_LEN * dirx[s]) + GRIDN) & (GRIDN - 1);
        int gy = ((int)rintf(py + SENSOR_LEN * diry[s]) + GRIDN) & (GRIDN - 1);
        const float4* p = (const float4*)(BT + ((size_t)(gx << 10) + gy) * CCH);
        float4 a = p[0], b = p[1];
        xin[s * 8 + 0] = a.x; xin[s * 8 + 1] = a.y;
        xin[s * 8 + 2] = a.z; xin[s * 8 + 3] = a.w;
        xin[s * 8 + 4] = b.x; xin[s * 8 + 5] = b.y;
        xin[s * 8 + 6] = b.z; xin[s * 8 + 7] = b.w;
    }

    // layer 1: h = tanh(x @ W1 + b1); W1 is (24, 64) row-major
    float h[HIDDEN];
#pragma unroll
    for (int j = 0; j < HIDDEN; ++j) h[j] = b1[j];
    for (int ii = 0; ii < 3 * CCH; ++ii) {
        float xi = xin[ii];
        const float* w = W1 + ii * HIDDEN;
#pragma unroll
        for (int j = 0; j < HIDDEN; ++j) h[j] = fmaf(xi, w[j], h[j]);
    }

    // layer 2: o = tanh(h) @ W2 + b2; W2 is (64, 10) row-major
    float o[2 + CCH];
#pragma unroll
    for (int k = 0; k < 2 + CCH; ++k) o[k] = b2[k];
    for (int j = 0; j < HIDDEN; ++j) {
        float t = tanhf(h[j]);
        const float* w2 = W2 + j * (2 + CCH);
#pragma unroll
        for (int k = 0; k < 2 + CCH; ++k) o[k] = fmaf(t, w2[k], o[k]);
    }

    float nvx = o[0], nvy = o[1];
    float npx = fmodf(px + nvx * DT, (float)GRIDN);
    if (npx < 0.f) npx += (float)GRIDN;
    float npy = fmodf(py + nvy * DT, (float)GRIDN);
    if (npy < 0.f) npy += (float)GRIDN;

    out_pos[i] = npx;
    out_pos[i + NAGENTS] = npy;
    out_vel[i] = nvx;
    out_vel[i + NAGENTS] = nvy;

    float4* dpp = (float4*)(dp + (size_t)i * CCH);
    dpp[0] = make_float4(o[2], o[3], o[4], o[5]);
    dpp[1] = make_float4(o[6], o[7], o[8], o[9]);
}

__global__ void __launch_bounds__(256) k_update(const float* __restrict__ lat,
                                                const int* __restrict__ winner,
                                                const float* __restrict__ dp,
                                                float* __restrict__ out_lat) {
    int idx = blockIdx.x * blockDim.x + threadIdx.x;  // cell index
    int w = winner[idx];
    float d[CCH];
    if (w >= 0) {
        const float4* dpp = (const float4*)(dp + (size_t)w * CCH);
        float4 a = dpp[0], b = dpp[1];
        d[0] = a.x; d[1] = a.y; d[2] = a.z; d[3] = a.w;
        d[4] = b.x; d[5] = b.y; d[6] = b.z; d[7] = b.w;
    }
#pragma unroll
    for (int c = 0; c < CCH; ++c) {
        size_t off = (size_t)c * GRIDN * GRIDN + idx;
        float v = lat[off];
        if (w >= 0) v = fmaxf(v + DT * d[c], 0.f);
        out_lat[off] = v * DECAYF;
    }
}

extern "C" void kernel_launch(void* const* d_in, const int* in_sizes, int n_in,
                              void* d_out, int out_size, void* d_ws, size_t ws_size,
                              hipStream_t stream) {
    const float* pos = (const float*)d_in[0];
    const float* vel = (const float*)d_in[1];
    const float* lat = (const float*)d_in[2];
    const float* W1  = (const float*)d_in[3];
    const float* b1  = (const float*)d_in[4];
    const float* W2  = (const float*)d_in[5];
    const float* b2  = (const float*)d_in[6];

    float* out      = (float*)d_out;
    float* out_pos  = out;                 // (2, N)
    float* out_vel  = out + 2 * NAGENTS;   // (2, N)
    float* out_lat  = out + 4 * NAGENTS;   // (C, G, G)

    char* ws = (char*)d_ws;
    int*   winner = (int*)ws;                       // 4 MB
    float* dp     = (float*)(ws + (4 << 20));       // 8 MB
    float* BT     = (float*)(ws + (12 << 20));      // 32 MB

    const int ncell = GRIDN * GRIDN;

    k_init_winner<<<ncell / 4 / 256, 256, 0, stream>>>(winner);
    k_winner<<<NAGENTS / 256, 256, 0, stream>>>(pos, winner);
    k_boxT<<<ncell / 256, 256, 0, stream>>>(lat, BT);
    k_agent<<<NAGENTS / 256, 256, 0, stream>>>(pos, vel, BT, W1, b1, W2, b2,
                                               out_pos, out_vel, dp);
    k_update<<<ncell / 256, 256, 0, stream>>>(lat, winner, dp, out_lat);
}

// Round 2
// 74.417 us; speedup vs baseline: 1.5020x; 1.5020x over previous
//
#include <hip/hip_runtime.h>
#include <hip/hip_bf16.h>
#include <math.h>

#define GRIDN 1024
#define NAGENTS 262144
#define CCH 8
#define HIDDEN 64
#define DT 0.1f
#define DECAYF 0.99f
#define SENSOR_LEN 3.0f
// cos(0.6), sin(0.6)
#define COS_SA 0.82533561490967829724f
#define SIN_SA 0.56464247339503535720f

typedef __attribute__((ext_vector_type(8))) short short8;

// tanh(x) = (2^(2x*log2e) - 1) / (2^(2x*log2e) + 1), clamped so exp2 can't overflow
__device__ __forceinline__ float fast_tanh(float x) {
    float xc = fminf(fmaxf(x, -9.0f), 9.0f);
    float t = __builtin_amdgcn_exp2f(xc * 2.88539008177792681472f);  // 2*log2(e)
    return (t - 1.0f) * __builtin_amdgcn_rcpf(t + 1.0f);
}

__global__ void __launch_bounds__(256) k_winner(const float* __restrict__ pos,
                                                int* __restrict__ winner) {
    int i = blockIdx.x * blockDim.x + threadIdx.x;
    int gx = (int)rintf(pos[i]) & (GRIDN - 1);
    int gy = (int)rintf(pos[i + NAGENTS]) & (GRIDN - 1);
    atomicMax(&winner[(gx << 10) + gy], i);
}

// BT[x][y][c] = 3x3 torus box sum of lattice channel c at (x,y), stored bf16.
// Also initializes winner[idx] = -1 (fused to save a dispatch).
__global__ void __launch_bounds__(256) k_boxT(const float* __restrict__ lat,
                                              __hip_bfloat16* __restrict__ BT,
                                              int* __restrict__ winner) {
    int idx = blockIdx.x * blockDim.x + threadIdx.x;  // 0 .. 1M-1
    winner[idx] = -1;
    int x = idx >> 10, y = idx & (GRIDN - 1);
    int xm = (x + GRIDN - 1) & (GRIDN - 1), xp = (x + 1) & (GRIDN - 1);
    int ym = (y + GRIDN - 1) & (GRIDN - 1), yp = (y + 1) & (GRIDN - 1);
    __hip_bfloat16 out[CCH];
#pragma unroll
    for (int c = 0; c < CCH; ++c) {
        const float* L = lat + (size_t)c * GRIDN * GRIDN;
        const float* r0 = L + xm * GRIDN;
        const float* r1 = L + x * GRIDN;
        const float* r2 = L + xp * GRIDN;
        float s = r0[ym] + r0[y] + r0[yp]
                + r1[ym] + r1[y] + r1[yp]
                + r2[ym] + r2[y] + r2[yp];
        out[c] = __float2bfloat16(s);
    }
    *(short8*)(BT + (size_t)idx * CCH) = *(const short8*)out;
}

__global__ void __launch_bounds__(256) k_agent(
    const float* __restrict__ pos, const float* __restrict__ vel,
    const __hip_bfloat16* __restrict__ BT,
    const float* __restrict__ W1, const float* __restrict__ b1,
    const float* __restrict__ W2, const float* __restrict__ b2,
    float* __restrict__ out_pos, float* __restrict__ out_vel,
    float* __restrict__ dp) {
    int i = blockIdx.x * blockDim.x + threadIdx.x;
    float px = pos[i], py = pos[i + NAGENTS];
    float vx = vel[i], vy = vel[i + NAGENTS];

    float r2 = vx * vx + vy * vy;
    float ct, st;
    if (r2 > 0.f) {
        float inv = rsqrtf(r2);
        ct = vx * inv;
        st = vy * inv;
    } else {
        ct = 1.f;  // atan2(0,0) = 0
        st = 0.f;
    }

    // sensor direction cosines: front, +0.6 (left), -0.6 (right)
    float dirx[3], diry[3];
    dirx[0] = ct;                          diry[0] = st;
    dirx[1] = ct * COS_SA - st * SIN_SA;   diry[1] = st * COS_SA + ct * SIN_SA;
    dirx[2] = ct * COS_SA + st * SIN_SA;   diry[2] = st * COS_SA - ct * SIN_SA;

    // issue all three gathers up front (independent 16B loads)
    short8 raw[3];
#pragma unroll
    for (int s = 0; s < 3; ++s) {
        int gx = ((int)rintf(px + SENSOR_LEN * dirx[s]) + GRIDN) & (GRIDN - 1);
        int gy = ((int)rintf(py + SENSOR_LEN * diry[s]) + GRIDN) & (GRIDN - 1);
        raw[s] = *(const short8*)(BT + ((size_t)(gx << 10) + gy) * CCH);
    }

    float xin[3 * CCH];
#pragma unroll
    for (int s = 0; s < 3; ++s)
#pragma unroll
        for (int c = 0; c < CCH; ++c) {
            unsigned u = ((unsigned)(unsigned short)raw[s][c]) << 16;
            xin[s * CCH + c] = __builtin_bit_cast(float, u);
        }

    // layer 1: h = x @ W1 + b1; W1 is (24, 64) row-major
    float h[HIDDEN];
#pragma unroll
    for (int j = 0; j < HIDDEN; ++j) h[j] = b1[j];
    for (int ii = 0; ii < 3 * CCH; ++ii) {
        float xi = xin[ii];
        const float* w = W1 + ii * HIDDEN;
#pragma unroll
        for (int j = 0; j < HIDDEN; ++j) h[j] = fmaf(xi, w[j], h[j]);
    }

    // layer 2: o = tanh(h) @ W2 + b2; W2 is (64, 10) row-major
    float o[2 + CCH];
#pragma unroll
    for (int k = 0; k < 2 + CCH; ++k) o[k] = b2[k];
    for (int j = 0; j < HIDDEN; ++j) {
        float t = fast_tanh(h[j]);
        const float* w2 = W2 + j * (2 + CCH);
#pragma unroll
        for (int k = 0; k < 2 + CCH; ++k) o[k] = fmaf(t, w2[k], o[k]);
    }

    float nvx = o[0], nvy = o[1];
    // pos in [2,1022], |vel*DT| tiny -> at most one wrap either side
    float npx = px + nvx * DT;
    if (npx >= (float)GRIDN) npx -= (float)GRIDN;
    if (npx < 0.f) npx += (float)GRIDN;
    float npy = py + nvy * DT;
    if (npy >= (float)GRIDN) npy -= (float)GRIDN;
    if (npy < 0.f) npy += (float)GRIDN;

    out_pos[i] = npx;
    out_pos[i + NAGENTS] = npy;
    out_vel[i] = nvx;
    out_vel[i + NAGENTS] = nvy;

    float4* dpp = (float4*)(dp + (size_t)i * CCH);
    dpp[0] = make_float4(o[2], o[3], o[4], o[5]);
    dpp[1] = make_float4(o[6], o[7], o[8], o[9]);
}

__global__ void __launch_bounds__(256) k_update(const float* __restrict__ lat,
                                                const int* __restrict__ winner,
                                                const float* __restrict__ dp,
                                                float* __restrict__ out_lat) {
    int idx = blockIdx.x * blockDim.x + threadIdx.x;  // cell index
    int w = winner[idx];
    float d[CCH];
    if (w >= 0) {
        const float4* dpp = (const float4*)(dp + (size_t)w * CCH);
        float4 a = dpp[0], b = dpp[1];
        d[0] = a.x; d[1] = a.y; d[2] = a.z; d[3] = a.w;
        d[4] = b.x; d[5] = b.y; d[6] = b.z; d[7] = b.w;
    }
#pragma unroll
    for (int c = 0; c < CCH; ++c) {
        size_t off = (size_t)c * GRIDN * GRIDN + idx;
        float v = lat[off];
        if (w >= 0) v = fmaxf(v + DT * d[c], 0.f);
        out_lat[off] = v * DECAYF;
    }
}

extern "C" void kernel_launch(void* const* d_in, const int* in_sizes, int n_in,
                              void* d_out, int out_size, void* d_ws, size_t ws_size,
                              hipStream_t stream) {
    const float* pos = (const float*)d_in[0];
    const float* vel = (const float*)d_in[1];
    const float* lat = (const float*)d_in[2];
    const float* W1  = (const float*)d_in[3];
    const float* b1  = (const float*)d_in[4];
    const float* W2  = (const float*)d_in[5];
    const float* b2  = (const float*)d_in[6];

    float* out      = (float*)d_out;
    float* out_pos  = out;                 // (2, N)
    float* out_vel  = out + 2 * NAGENTS;   // (2, N)
    float* out_lat  = out + 4 * NAGENTS;   // (C, G, G)

    char* ws = (char*)d_ws;
    int*            winner = (int*)ws;                          // 4 MB
    float*          dp     = (float*)(ws + (4 << 20));          // 8 MB
    __hip_bfloat16* BT     = (__hip_bfloat16*)(ws + (12 << 20)); // 16 MB

    const int ncell = GRIDN * GRIDN;

    k_boxT<<<ncell / 256, 256, 0, stream>>>(lat, BT, winner);
    k_winner<<<NAGENTS / 256, 256, 0, stream>>>(pos, winner);
    k_agent<<<NAGENTS / 256, 256, 0, stream>>>(pos, vel, BT, W1, b1, W2, b2,
                                               out_pos, out_vel, dp);
    k_update<<<ncell / 256, 256, 0, stream>>>(lat, winner, dp, out_lat);
}